// Round 1
// 10268.793 us; speedup vs baseline: 1.3483x; 1.3483x over previous
//
#include <hip/hip_runtime.h>
#include <hip/hip_bf16.h>

// Problem constants (B=256, T=512, H=512, IN=1, future=64)
#define TT  512
#define BB  256
#define HH  512
#define FUT 64
#define NBLK 128           // 64 unit-groups x 2 batch-groups

// Output dtype FP32 (r6/r7 verified). Beacons: float 2^(20+code)*(1+m/128):
//  0: n_in!=22  1: in_sizes mismatch @m  2: ws too small  6: out_size wrong
// r13: upb=8 (8 units/block, 96KB weight LDS, 128 blocks -> coherent h-read
// volume halved) + coalescable 16B sc0/sc1 asm loads with counted vmcnt
// waits (replaces 2x8B system atomics; ~8x fewer fabric requests).
// Coherence scheme = r11 (fence-free; h via sc0sc1 ops; caches never flushed).

struct Hdr { int dtflag; };

typedef __attribute__((ext_vector_type(8))) short short8;
typedef __attribute__((ext_vector_type(4))) float floatx4;

#define OFF_CTR   4096
#define OFF_W     8192
#define WSZ       ((size_t)2048*512*2)          // 2MB bf16 matrix
#define OFF_H     (OFF_W + 6*WSZ)
#define HSZ       ((size_t)BB*HH*2)             // 256KB bf16 state
#define NEED_WS   (OFF_H + 4*HSZ)               // ~13.6MB

__device__ __forceinline__ float bf2f(short s) {
  unsigned u = ((unsigned)(unsigned short)s) << 16;
  return __builtin_bit_cast(float, u);
}
__device__ __forceinline__ short f2bf(float f) {
  unsigned u = __builtin_bit_cast(unsigned, f);
  u = u + 0x7FFFu + ((u >> 16) & 1u);
  return (short)(u >> 16);
}
__device__ __forceinline__ float ldf(const void* p, long i, int dt) {
  return dt ? ((const float*)p)[i] : bf2f(((const short*)p)[i]);
}
// 16B coherence-point load: single dwordx4 with sc0 sc1 (same cache-bypass
// bits the compiler emits for system-scope relaxed atomics; coalesces).
// NOTE: result is NOT ready until a manual s_waitcnt vmcnt(N) — see WAITV.
__device__ __forceinline__ short8 cohld16(const short* p) {
  short8 v;
  asm volatile("global_load_dwordx4 %0, %1, off sc0 sc1"
               : "=v"(v) : "v"(p));
  return v;
}
// counted wait + hard scheduling fence (rule #18: keep MFMA below the wait)
#define WAITV(N) do { asm volatile("s_waitcnt vmcnt(" #N ")" ::: "memory"); \
                      __builtin_amdgcn_sched_barrier(0); } while (0)

__global__ void beacon_kernel(float* dout, float v) {
  if (threadIdx.x == 0) dout[0] = v;
}

__global__ __launch_bounds__(256) void probe1_kernel(const void* w, Hdr* hdr) {
  const int tid = threadIdx.x;
  const short* s = (const short*)w;
  float mx = 0.f;
  #pragma unroll
  for (int i = 0; i < 16; ++i) {
    float v = fabsf(bf2f(s[tid * 16 + i]));
    if (!(v == v)) v = 1e30f;
    mx = fmaxf(mx, v);
  }
  #pragma unroll
  for (int off = 32; off > 0; off >>= 1) mx = fmaxf(mx, __shfl_down(mx, off));
  __shared__ float wmax[4];
  if ((tid & 63) == 0) wmax[tid >> 6] = mx;
  __syncthreads();
  if (tid == 0) {
    float m = fmaxf(fmaxf(wmax[0], wmax[1]), fmaxf(wmax[2], wmax[3]));
    hdr->dtflag = (m > 1000.f) ? 1 : 0;
  }
}

__global__ __launch_bounds__(256) void cvt_kernel(const void* src, short* dst,
                                                  const Hdr* hdr) {
  const int dt = hdr->dtflag;
  const long i = ((long)blockIdx.x * 256 + threadIdx.x);
  if (dt) {
    const float4 v = ((const float4*)src)[i];
    short4 o;
    o.x = f2bf(v.x); o.y = f2bf(v.y); o.z = f2bf(v.z); o.w = f2bf(v.w);
    ((short4*)dst)[i] = o;
  } else {
    ((short4*)dst)[i] = ((const short4*)src)[i];
  }
}

// Persistent 2-layer LSTM, 8 units/block, LDS weights, fence-free coherence.
__global__ __launch_bounds__(256, 1) void lstm_persist(
    const void* __restrict__ x,
    const void* __restrict__ w_ih0, const void* __restrict__ b_ih0,
    const void* __restrict__ b_hh0, const void* __restrict__ b_ih1,
    const void* __restrict__ b_hh1, const void* __restrict__ fc_w,
    const void* __restrict__ fc_b,  const void* __restrict__ pw_ih0,
    const void* __restrict__ pb_ih0, const void* __restrict__ pb_hh0,
    const void* __restrict__ pb_ih1, const void* __restrict__ pb_hh1,
    const void* __restrict__ pfc_w, const void* __restrict__ pfc_b,
    const short* __restrict__ Whh0, const short* __restrict__ Wih1,
    const short* __restrict__ Whh1, const short* __restrict__ pWhh0,
    const short* __restrict__ pWih1, const short* __restrict__ pWhh1,
    short* H0a, short* H0b, short* H1a, short* H1b,
    int* ctr, const Hdr* __restrict__ hdr, float* __restrict__ dout)
{
  const int dt  = hdr->dtflag;
  const int tid = threadIdx.x;
  const int ug  = blockIdx.x >> 1;     // 0..63
  const int bg  = blockIdx.x & 1;      // 0..1
  const int U0  = ug * 8;
  const int B0  = bg * 128;
  int* grpArr = ctr + 32 + (blockIdx.x >> 4) * 32;        // arrive line
  int* grpRel = ctr + 32 + (blockIdx.x >> 4) * 32 + 16;   // release line
  const int isMaster = (blockIdx.x & 15) == 0;            // 8 masters

  __shared__ __align__(16) short Wl[3][64][32][8]; // 96 KB: [slot][kseg][row][8]
  __shared__ float xch[128][8][4];     // 16 KB gate exchange
  __shared__ float bs[3][32];          // [0] L0 bias, [1] L1 bias, [2] wih col
  __shared__ float obuf[128];

  const int lane = tid & 63;
  const int wv   = tid >> 6;           // m-half 0..3 (32 batches each)
  const int n    = lane & 15;
  const int q    = lane >> 4;
  const long abase = (long)(B0 + wv*32 + n) * 512 + q*8;

  const int eb = tid >> 1;             // epilogue batch 0..127
  const int eu = (tid & 1) * 4;        // 4 units per thread
  float c0[4] = {0.f,0.f,0.f,0.f}, c1[4] = {0.f,0.f,0.f,0.f};

  short *h0c = H0a, *h0n = H0b, *h1c = H1a, *h1n = H1b;
  int ph = 0;

// stage one 32KB weight slot: rows = gate*8+unit (32), ksegs = 64
#define STAGE(SLOT, WG)                                                      \
  for (int i = tid; i < 2048; i += 256) {                                    \
    const int r = i & 31, s_ = i >> 5;                                       \
    const int k0 = (s_ & 3) * 8 + (s_ >> 2) * 32;                            \
    const long gr = (long)((r >> 3) * 512 + U0 + (r & 7)) * 512 + k0;        \
    *(short8*)&Wl[SLOT][s_][r][0] = *(const short8*)((WG) + gr);             \
  }

// flat idx 0..31: m2 = idx>>4, kb = idx&15. A-offset helper.
#define AOFF(IDX) ((long)((IDX) >> 4) * 16 * 512 + ((IDX) & 15) * 32)

// pipelined single-W pass: 4 groups of 8 loads, counted-vmcnt double buffer
#define GSEG1(AP, SLOT, ACC)                                                 \
  { const short* ap_ = (AP) + abase;                                         \
    short8 abuf[2][8];                                                       \
    _Pragma("unroll")                                                        \
    for (int i = 0; i < 8; ++i) abuf[0][i] = cohld16(ap_ + AOFF(i));         \
    _Pragma("unroll")                                                        \
    for (int g = 0; g < 4; ++g) {                                            \
      if (g < 3) {                                                           \
        _Pragma("unroll")                                                    \
        for (int i = 0; i < 8; ++i)                                          \
          abuf[(g + 1) & 1][i] = cohld16(ap_ + AOFF((g + 1) * 8 + i));       \
        WAITV(8);                                                            \
      } else {                                                               \
        WAITV(0);                                                            \
      }                                                                      \
      _Pragma("unroll")                                                      \
      for (int i = 0; i < 8; ++i) {                                          \
        const int idx = g * 8 + i;                                           \
        const int ks = (idx & 15) * 4 + q;                                   \
        const int mh = (idx >> 4) * 2;                                       \
        short8 b;                                                            \
        b = *(const short8*)&Wl[SLOT][ks][n][0];                             \
        ACC[mh] = __builtin_amdgcn_mfma_f32_16x16x32_bf16(                   \
            abuf[g & 1][i], b, ACC[mh], 0, 0, 0);                            \
        b = *(const short8*)&Wl[SLOT][ks][16 + n][0];                        \
        ACC[mh+1] = __builtin_amdgcn_mfma_f32_16x16x32_bf16(                 \
            abuf[g & 1][i], b, ACC[mh+1], 0, 0, 0);                          \
      }                                                                      \
    } }

// pipelined dual-W pass (one h stream feeds two weight slots)
#define GSEG2(AP, S0, S1, A0, A1, DUAL)                                      \
  { const short* ap_ = (AP) + abase;                                         \
    short8 abuf[2][8];                                                       \
    _Pragma("unroll")                                                        \
    for (int i = 0; i < 8; ++i) abuf[0][i] = cohld16(ap_ + AOFF(i));         \
    _Pragma("unroll")                                                        \
    for (int g = 0; g < 4; ++g) {                                            \
      if (g < 3) {                                                           \
        _Pragma("unroll")                                                    \
        for (int i = 0; i < 8; ++i)                                          \
          abuf[(g + 1) & 1][i] = cohld16(ap_ + AOFF((g + 1) * 8 + i));       \
        WAITV(8);                                                            \
      } else {                                                               \
        WAITV(0);                                                            \
      }                                                                      \
      _Pragma("unroll")                                                      \
      for (int i = 0; i < 8; ++i) {                                          \
        const int idx = g * 8 + i;                                           \
        const int ks = (idx & 15) * 4 + q;                                   \
        const int mh = (idx >> 4) * 2;                                       \
        short8 b;                                                            \
        b = *(const short8*)&Wl[S0][ks][n][0];                               \
        A0[mh] = __builtin_amdgcn_mfma_f32_16x16x32_bf16(                    \
            abuf[g & 1][i], b, A0[mh], 0, 0, 0);                             \
        b = *(const short8*)&Wl[S0][ks][16 + n][0];                          \
        A0[mh+1] = __builtin_amdgcn_mfma_f32_16x16x32_bf16(                  \
            abuf[g & 1][i], b, A0[mh+1], 0, 0, 0);                           \
        if (DUAL) {                                                          \
          b = *(const short8*)&Wl[S1][ks][n][0];                             \
          A1[mh] = __builtin_amdgcn_mfma_f32_16x16x32_bf16(                  \
              abuf[g & 1][i], b, A1[mh], 0, 0, 0);                           \
          b = *(const short8*)&Wl[S1][ks][16 + n][0];                        \
          A1[mh+1] = __builtin_amdgcn_mfma_f32_16x16x32_bf16(                \
              abuf[g & 1][i], b, A1[mh+1], 0, 0, 0);                         \
        }                                                                    \
      }                                                                      \
    } }

// D tile: row(batch-in-16) = q*4+r, col = n -> weight row nt*16+n
#define XCHW(ACC)                                                            \
  __syncthreads();                                                           \
  _Pragma("unroll")                                                          \
  for (int m2 = 0; m2 < 2; ++m2)                                             \
    _Pragma("unroll")                                                        \
    for (int nt = 0; nt < 2; ++nt)                                           \
      _Pragma("unroll")                                                      \
      for (int r = 0; r < 4; ++r) {                                          \
        const int row = nt*16 + n;                                           \
        xch[wv*32 + m2*16 + q*4 + r][row & 7][row >> 3] = ACC[m2*2+nt][r];   \
      }                                                                      \
  __syncthreads();

#define EPI(BSI, MODE, TV, CREG, HOUT)                                       \
  { float sv = 0.f;                                                          \
    if ((MODE) == 0)      sv = ldf(x, (long)(B0 + eb)*TT + (TV), dt);        \
    else if ((MODE) == 2) sv = obuf[eb];                                     \
    union { unsigned long long qv; short s[4]; } hv;                         \
    _Pragma("unroll")                                                        \
    for (int j = 0; j < 4; ++j) {                                            \
      const int u = eu + j;                                                  \
      float gi = xch[eb][u][0] + bs[BSI][u];                                 \
      float gf = xch[eb][u][1] + bs[BSI][8 + u];                             \
      float gg = xch[eb][u][2] + bs[BSI][16 + u];                            \
      float go = xch[eb][u][3] + bs[BSI][24 + u];                            \
      if ((MODE) != 1) {                                                     \
        gi += sv * bs[2][u];       gf += sv * bs[2][8 + u];                  \
        gg += sv * bs[2][16 + u];  go += sv * bs[2][24 + u];                 \
      }                                                                      \
      const float I = 1.f/(1.f+expf(-gi));                                   \
      const float F = 1.f/(1.f+expf(-gf));                                   \
      const float G = tanhf(gg);                                             \
      const float O = 1.f/(1.f+expf(-go));                                   \
      const float cn = F*(CREG)[j] + I*G;                                    \
      (CREG)[j] = cn;                                                        \
      hv.s[j] = f2bf(O * tanhf(cn));                                         \
    }                                                                        \
    __hip_atomic_store(                                                      \
        (unsigned long long*)((HOUT) + (long)(B0+eb)*512 + U0 + eu),         \
        hv.qv, __ATOMIC_RELAXED, __HIP_MEMORY_SCOPE_SYSTEM);                 \
  }

// fence-free barrier: 8 groups of 16, per-group release line
#define GBAR()                                                               \
  { __syncthreads();                                                         \
    ++ph;                                                                    \
    if (tid == 0) {                                                          \
      asm volatile("s_waitcnt vmcnt(0)" ::: "memory");                       \
      __hip_atomic_fetch_add(grpArr, 1, __ATOMIC_RELAXED,                    \
                             __HIP_MEMORY_SCOPE_SYSTEM);                     \
      if (isMaster) {                                                        \
        while (__hip_atomic_load(grpArr, __ATOMIC_RELAXED,                   \
                                 __HIP_MEMORY_SCOPE_SYSTEM) < ph * 16)       \
          __builtin_amdgcn_s_sleep(1);                                       \
        __hip_atomic_fetch_add(ctr, 1, __ATOMIC_RELAXED,                     \
                               __HIP_MEMORY_SCOPE_SYSTEM);                   \
        while (__hip_atomic_load(ctr, __ATOMIC_RELAXED,                      \
                                 __HIP_MEMORY_SCOPE_SYSTEM) < ph * 8)        \
          __builtin_amdgcn_s_sleep(1);                                       \
        __hip_atomic_store(grpRel, ph, __ATOMIC_RELAXED,                     \
                           __HIP_MEMORY_SCOPE_SYSTEM);                       \
      } else {                                                               \
        while (__hip_atomic_load(grpRel, __ATOMIC_RELAXED,                   \
                                 __HIP_MEMORY_SCOPE_SYSTEM) < ph)            \
          __builtin_amdgcn_s_sleep(1);                                       \
      }                                                                      \
    }                                                                        \
    __syncthreads();                                                         \
  }

#define HEAD(H1C, FW, FB, S)                                                 \
  { const int hb = tid >> 1, hf = tid & 1;                                   \
    const short* hp = (H1C) + (long)(B0 + hb)*512 + hf*256;                  \
    float sum = 0.f;                                                         \
    for (int g4 = 0; g4 < 4; ++g4) {                                         \
      short8 habuf[8];                                                       \
      _Pragma("unroll")                                                      \
      for (int i = 0; i < 8; ++i) habuf[i] = cohld16(hp + (g4*8 + i)*8);     \
      WAITV(0);                                                              \
      _Pragma("unroll")                                                      \
      for (int i = 0; i < 8; ++i)                                            \
        _Pragma("unroll")                                                    \
        for (int j = 0; j < 8; ++j)                                          \
          sum += bf2f(habuf[i][j]) * ldf((FW), hf*256 + (g4*8+i)*8 + j, dt); \
    }                                                                        \
    sum += __shfl_xor(sum, 1);                                               \
    if (hf == 0) {                                                           \
      float o = sum + ldf((FB), 0, dt);                                      \
      obuf[hb] = o;                                                          \
      if (ug == 0) dout[(long)(B0 + hb)*FUT + (S)] = o;                      \
    }                                                                        \
    __syncthreads();                                                         \
  }

  // ---- one-time staging: warmup weights + biases ----
  STAGE(0, Whh0); STAGE(1, Wih1); STAGE(2, Whh1);
  if (tid < 32) {
    const long j = (long)(tid >> 3)*512 + U0 + (tid & 7);
    bs[0][tid] = ldf(b_ih0, j, dt) + ldf(b_hh0, j, dt);
    bs[1][tid] = ldf(b_ih1, j, dt) + ldf(b_hh1, j, dt);
    bs[2][tid] = ldf(w_ih0, j, dt);
  }
  __syncthreads();

  // ---- warmup: phase t = L0(t) || L1(t-1), one barrier each ----
  for (int t = 0; t < TT; ++t) {
    floatx4 a0[4] = {{0,0,0,0},{0,0,0,0},{0,0,0,0},{0,0,0,0}};
    floatx4 a1[4] = {{0,0,0,0},{0,0,0,0},{0,0,0,0},{0,0,0,0}};
    GSEG2(h0c, 0, 1, a0, a1, (t > 0));   // one h0 pass feeds Whh0 + Wih1
    XCHW(a0);
    EPI(0, 0, t, c0, h0n);
    if (t > 0) {
      GSEG1(h1c, 2, a1);
      XCHW(a1);
      EPI(1, 1, 0, c1, h1n);
      { short* tmp = h1c; h1c = h1n; h1n = tmp; }
    }
    { short* tmp = h0c; h0c = h0n; h0n = tmp; }
    GBAR();
  }
  // final L1(511)
  { floatx4 a1[4] = {{0,0,0,0},{0,0,0,0},{0,0,0,0},{0,0,0,0}};
    GSEG1(h0c, 1, a1); GSEG1(h1c, 2, a1); XCHW(a1);
    EPI(1, 1, 0, c1, h1n);
    { short* tmp = h1c; h1c = h1n; h1n = tmp; } }
  GBAR();
  HEAD(h1c, fc_w, fc_b, 0);

  // ---- transition: stage decode weights + biases (block-local) ----
  STAGE(0, pWhh0); STAGE(1, pWih1); STAGE(2, pWhh1);
  if (tid < 32) {
    const long j = (long)(tid >> 3)*512 + U0 + (tid & 7);
    bs[0][tid] = ldf(pb_ih0, j, dt) + ldf(pb_hh0, j, dt);
    bs[1][tid] = ldf(pb_ih1, j, dt) + ldf(pb_hh1, j, dt);
    bs[2][tid] = ldf(pw_ih0, j, dt);
  }
  __syncthreads();

  // ---- decode: 63 steps, 2 barriers each ----
  for (int s = 1; s < FUT; ++s) {
    { floatx4 a0[4] = {{0,0,0,0},{0,0,0,0},{0,0,0,0},{0,0,0,0}};
      GSEG1(h0c, 0, a0); XCHW(a0); }
    EPI(0, 2, 0, c0, h0n);
    { short* tmp = h0c; h0c = h0n; h0n = tmp; }
    GBAR();
    { floatx4 a1[4] = {{0,0,0,0},{0,0,0,0},{0,0,0,0},{0,0,0,0}};
      GSEG1(h0c, 1, a1); GSEG1(h1c, 2, a1); XCHW(a1);
      EPI(1, 1, 0, c1, h1n); }
    { short* tmp = h1c; h1c = h1n; h1n = tmp; }
    GBAR();
    HEAD(h1c, pfc_w, pfc_b, s);
  }
#undef STAGE
#undef GSEG2
#undef GSEG1
#undef XCHW
#undef EPI
#undef GBAR
#undef HEAD
#undef AOFF
}

extern "C" void kernel_launch(void* const* d_in, const int* in_sizes, int n_in,
                              void* d_out, int out_size, void* d_ws, size_t ws_size,
                              hipStream_t stream) {
  float* dout = (float*)d_out;

  static const int exp_sizes[22] = {
    131072, 1, 2048, 1048576, 2048, 2048, 1048576, 1048576, 2048, 2048,
    512, 1, 2048, 1048576, 2048, 2048, 1048576, 1048576, 2048, 2048, 512, 1};
  int code = -1, m = 0;
  if (n_in != 22) { code = 0; m = n_in & 127; }
  else {
    for (int i = 0; i < 22; ++i)
      if (in_sizes[i] != exp_sizes[i]) { code = 1; m = i; break; }
  }
  if (code < 0 && out_size != BB * FUT) { code = 6; m = (out_size >> 8) & 127; }
  if (code < 0 && (d_ws == nullptr || ws_size < NEED_WS)) {
    code = 2; m = (int)(ws_size >> 20); if (m > 127) m = 127;
  }
  if (code >= 0) {
    float v = ldexpf(1.f + (float)m / 128.f, 20 + code);
    beacon_kernel<<<dim3(1), dim3(64), 0, stream>>>(dout, v);
    return;
  }

  const void* x      = d_in[0];
  const void* w_ih0  = d_in[2];
  const void* w_hh0  = d_in[3];
  const void* b_ih0  = d_in[4];
  const void* b_hh0  = d_in[5];
  const void* w_ih1  = d_in[6];
  const void* w_hh1  = d_in[7];
  const void* b_ih1  = d_in[8];
  const void* b_hh1  = d_in[9];
  const void* fc_w   = d_in[10];
  const void* fc_b   = d_in[11];
  const void* pw_ih0 = d_in[12];
  const void* pw_hh0 = d_in[13];
  const void* pb_ih0 = d_in[14];
  const void* pb_hh0 = d_in[15];
  const void* pw_ih1 = d_in[16];
  const void* pw_hh1 = d_in[17];
  const void* pb_ih1 = d_in[18];
  const void* pb_hh1 = d_in[19];
  const void* pfc_w  = d_in[20];
  const void* pfc_b  = d_in[21];

  char* ws = (char*)d_ws;
  Hdr* hdr = (Hdr*)ws;
  int* ctr = (int*)(ws + OFF_CTR);
  short* Wc[6];
  for (int i = 0; i < 6; ++i) Wc[i] = (short*)(ws + OFF_W + (size_t)i*WSZ);
  short* H0a = (short*)(ws + OFF_H);
  short* H0b = (short*)(ws + OFF_H + HSZ);
  short* H1a = (short*)(ws + OFF_H + 2*HSZ);
  short* H1b = (short*)(ws + OFF_H + 3*HSZ);

  hipMemsetAsync(ws, 0, 8192, stream);          // hdr + barrier counters
  hipMemsetAsync(H0a, 0, HSZ, stream);
  hipMemsetAsync(H1a, 0, HSZ, stream);
  probe1_kernel<<<dim3(1), dim3(256), 0, stream>>>(w_hh0, hdr);

  dim3 cg(1024), cb(256);
  cvt_kernel<<<cg, cb, 0, stream>>>(w_hh0,  Wc[0], hdr);
  cvt_kernel<<<cg, cb, 0, stream>>>(w_ih1,  Wc[1], hdr);
  cvt_kernel<<<cg, cb, 0, stream>>>(w_hh1,  Wc[2], hdr);
  cvt_kernel<<<cg, cb, 0, stream>>>(pw_hh0, Wc[3], hdr);
  cvt_kernel<<<cg, cb, 0, stream>>>(pw_ih1, Wc[4], hdr);
  cvt_kernel<<<cg, cb, 0, stream>>>(pw_hh1, Wc[5], hdr);

  lstm_persist<<<dim3(NBLK), dim3(256), 0, stream>>>(
      x, w_ih0, b_ih0, b_hh0, b_ih1, b_hh1, fc_w, fc_b,
      pw_ih0, pb_ih0, pb_hh0, pb_ih1, pb_hh1, pfc_w, pfc_b,
      Wc[0], Wc[1], Wc[2], Wc[3], Wc[4], Wc[5],
      H0a, H0b, H1a, H1b, ctr, hdr, dout);
}

// Round 2
// 8650.112 us; speedup vs baseline: 1.6006x; 1.1871x over previous
//
#include <hip/hip_runtime.h>
#include <hip/hip_bf16.h>

// Problem constants (B=256, T=512, H=512, IN=1, future=64)
#define TT  512
#define BB  256
#define HH  512
#define FUT 64
#define NBLK 128           // 2 roles x 32 unit-groups x 2 batch-groups

// Output dtype FP32. Beacons: float 2^(20+code)*(1+m/128):
//  0: n_in!=22  1: in_sizes mismatch @m  2: ws too small  6: out_size wrong
// r14: layer-split roles (64 L0-blocks / 64 L1-blocks, 16 units each).
// Operand-swapped MFMA (W as A-operand, unit-major rows) -> each lane holds
// all 4 gates of one (batch,unit) in acc regs: in-lane EPI, no xch, c-state
// stays in registers across warmup->decode. L1 reads h0+h1 in ONE dual-
// stream pipelined pass (single latency exposure). Coherence scheme = r11
// (fence-free; h via sc0sc1 ops; caches never flushed).

struct Hdr { int dtflag; };

typedef __attribute__((ext_vector_type(8))) short short8;
typedef __attribute__((ext_vector_type(4))) float floatx4;

#define OFF_CTR   4096
#define OFF_W     8192
#define WSZ       ((size_t)2048*512*2)          // 2MB bf16 matrix
#define OFF_H     (OFF_W + 6*WSZ)
#define HSZ       ((size_t)BB*HH*2)             // 256KB bf16 state
#define NEED_WS   (OFF_H + 4*HSZ)               // ~13.6MB

__device__ __forceinline__ float bf2f(short s) {
  unsigned u = ((unsigned)(unsigned short)s) << 16;
  return __builtin_bit_cast(float, u);
}
__device__ __forceinline__ short f2bf(float f) {
  unsigned u = __builtin_bit_cast(unsigned, f);
  u = u + 0x7FFFu + ((u >> 16) & 1u);
  return (short)(u >> 16);
}
__device__ __forceinline__ float ldf(const void* p, long i, int dt) {
  return dt ? ((const float*)p)[i] : bf2f(((const short*)p)[i]);
}
// 16B coherence-point load/store: dwordx4 with sc0 sc1 (bypasses L1/L2,
// same bits as system-scope relaxed atomics; coalesces). Result/data not
// ordered until manual s_waitcnt vmcnt(N) — see WAITV / GBAR.
__device__ __forceinline__ short8 cohld16(const short* p) {
  short8 v;
  asm volatile("global_load_dwordx4 %0, %1, off sc0 sc1"
               : "=v"(v) : "v"(p));
  return v;
}
__device__ __forceinline__ void cohst16(short* p, short8 v) {
  asm volatile("global_store_dwordx4 %0, %1, off sc0 sc1"
               :: "v"(p), "v"(v) : "memory");
}
// counted wait + hard scheduling fence (rule #18: keep MFMA below the wait)
#define WAITV(N) do { asm volatile("s_waitcnt vmcnt(" #N ")" ::: "memory"); \
                      __builtin_amdgcn_sched_barrier(0); } while (0)

__global__ void beacon_kernel(float* dout, float v) {
  if (threadIdx.x == 0) dout[0] = v;
}

__global__ __launch_bounds__(256) void probe1_kernel(const void* w, Hdr* hdr) {
  const int tid = threadIdx.x;
  const short* s = (const short*)w;
  float mx = 0.f;
  #pragma unroll
  for (int i = 0; i < 16; ++i) {
    float v = fabsf(bf2f(s[tid * 16 + i]));
    if (!(v == v)) v = 1e30f;
    mx = fmaxf(mx, v);
  }
  #pragma unroll
  for (int off = 32; off > 0; off >>= 1) mx = fmaxf(mx, __shfl_down(mx, off));
  __shared__ float wmax[4];
  if ((tid & 63) == 0) wmax[tid >> 6] = mx;
  __syncthreads();
  if (tid == 0) {
    float m = fmaxf(fmaxf(wmax[0], wmax[1]), fmaxf(wmax[2], wmax[3]));
    hdr->dtflag = (m > 1000.f) ? 1 : 0;
  }
}

__global__ __launch_bounds__(256) void cvt_kernel(const void* src, short* dst,
                                                  const Hdr* hdr) {
  const int dt = hdr->dtflag;
  const long i = ((long)blockIdx.x * 256 + threadIdx.x);
  if (dt) {
    const float4 v = ((const float4*)src)[i];
    short4 o;
    o.x = f2bf(v.x); o.y = f2bf(v.y); o.z = f2bf(v.z); o.w = f2bf(v.w);
    ((short4*)dst)[i] = o;
  } else {
    ((short4*)dst)[i] = ((const short4*)src)[i];
  }
}

// Persistent 2-layer LSTM, layer-split roles, LDS weights, fence-free coh.
__global__ __launch_bounds__(256, 1) void lstm_persist(
    const void* __restrict__ x,
    const void* __restrict__ w_ih0, const void* __restrict__ b_ih0,
    const void* __restrict__ b_hh0, const void* __restrict__ b_ih1,
    const void* __restrict__ b_hh1, const void* __restrict__ fc_w,
    const void* __restrict__ fc_b,  const void* __restrict__ pw_ih0,
    const void* __restrict__ pb_ih0, const void* __restrict__ pb_hh0,
    const void* __restrict__ pb_ih1, const void* __restrict__ pb_hh1,
    const void* __restrict__ pfc_w, const void* __restrict__ pfc_b,
    const short* __restrict__ Whh0, const short* __restrict__ Wih1,
    const short* __restrict__ Whh1, const short* __restrict__ pWhh0,
    const short* __restrict__ pWih1, const short* __restrict__ pWhh1,
    short* H0a, short* H0b, short* H1a, short* H1b,
    int* ctr, const Hdr* __restrict__ hdr, float* __restrict__ dout)
{
  const int dt  = hdr->dtflag;
  const int tid = threadIdx.x;
  const int role = blockIdx.x & 1;         // 0 = layer0, 1 = layer1
  const int bg   = (blockIdx.x >> 1) & 1;  // 0..1
  const int ug   = blockIdx.x >> 2;        // 0..31
  const int U0   = ug * 16;
  const int B0   = bg * 128;
  int* grpArr = ctr + 32 + (blockIdx.x >> 4) * 32;        // arrive line
  int* grpRel = ctr + 32 + (blockIdx.x >> 4) * 32 + 16;   // release line
  const int isMaster = (blockIdx.x & 15) == 0;            // 8 masters

  // 128KB weights: [slot][kseg(64)][row(64)][8]; row = unit_local*4 + gate,
  // kseg -> k = kseg*8. role0 uses slot0; role1 uses slot0(ih)+slot1(hh).
  __shared__ __align__(16) short Wl[2][64][64][8];
  __shared__ __align__(16) short hbuf[128][16];  // 4KB h repack
  __shared__ float bs[64];                       // bias, idx = u*4+gate
  __shared__ float wih[64];                      // w_ih col (L0 only)
  __shared__ float obuf[128];

  const int lane = tid & 63;
  const int wv   = tid >> 6;           // 32-batch half per wave
  const int ln   = lane & 15;          // batch-in-tile AND W-row-in-tile
  const int q    = lane >> 4;          // k-slice / unit-in-quad
  const long abase = (long)(B0 + wv*32 + ln) * 512 + q*8;

  // per-lane cell state for this role's layer: [mt][nt] ->
  // unit = U0 + mt*4 + q, batch = B0 + wv*32 + nt*16 + ln
  float cst[4][2] = {{0.f,0.f},{0.f,0.f},{0.f,0.f},{0.f,0.f}};

  short *h0c = H0a, *h0n = H0b, *h1c = H1a, *h1n = H1b;
  int ph = 0;

// stage one 64KB slot, global-coalesced (ds write conflicts are one-time)
#define STAGE16(SLOT, WG)                                                    \
  for (int i = tid; i < 4096; i += 256) {                                    \
    const int ks_ = i & 63, r_ = i >> 6;                                     \
    const long gr = (long)((r_ & 3) * 512 + U0 + (r_ >> 2)) * 512 + ks_ * 8; \
    *(short8*)&Wl[SLOT][ks_][r_][0] = *(const short8*)((WG) + gr);           \
  }

#define BIAS16(B1, B2, WIHP)                                                 \
  if (tid < 64) {                                                            \
    const long j = (long)(tid & 3) * 512 + U0 + (tid >> 2);                  \
    bs[tid] = ldf((B1), j, dt) + ldf((B2), j, dt);                           \
    wih[tid] = (WIHP) ? ldf((const void*)(WIHP), j, dt) : 0.f;               \
  }

#define ZACC(A)                                                              \
  _Pragma("unroll") for (int mt_ = 0; mt_ < 4; ++mt_)                        \
    _Pragma("unroll") for (int nt_ = 0; nt_ < 2; ++nt_)                      \
      A[mt_][nt_] = (floatx4){0.f, 0.f, 0.f, 0.f};

#define LOFF(KB, NT) ((long)(NT) * 16 * 512 + (KB) * 32)

// single-stream pass: K=512 as 16 kb; 4 groups x (4kb x 2nt) = 8 loads
#define GSEG1N(AP, ACC)                                                      \
  { const short* ap_ = (AP) + abase;                                         \
    short8 abuf[2][8];                                                       \
    _Pragma("unroll")                                                        \
    for (int u_ = 0; u_ < 8; ++u_)                                           \
      abuf[0][u_] = cohld16(ap_ + LOFF(u_ >> 1, u_ & 1));                    \
    _Pragma("unroll")                                                        \
    for (int g = 0; g < 4; ++g) {                                            \
      if (g < 3) {                                                           \
        _Pragma("unroll")                                                    \
        for (int u_ = 0; u_ < 8; ++u_)                                       \
          abuf[(g+1)&1][u_] = cohld16(ap_ + LOFF((g+1)*4 + (u_>>1), u_&1));  \
        WAITV(8);                                                            \
      } else { WAITV(0); }                                                   \
      _Pragma("unroll")                                                      \
      for (int kk = 0; kk < 4; ++kk) {                                       \
        const int kb = g*4 + kk;                                             \
        _Pragma("unroll")                                                    \
        for (int mt = 0; mt < 4; ++mt) {                                     \
          short8 wf = *(const short8*)&Wl[0][kb*4 + q][mt*16 + ln][0];       \
          _Pragma("unroll")                                                  \
          for (int nt = 0; nt < 2; ++nt)                                     \
            ACC[mt][nt] = __builtin_amdgcn_mfma_f32_16x16x32_bf16(           \
                wf, abuf[g&1][kk*2 + nt], ACC[mt][nt], 0, 0, 0);             \
        }                                                                    \
      }                                                                      \
    } }

// dual-stream pass: gates += Wl[0]*h(AP0) + Wl[1]*h(AP1); one latency
// exposure, 8 groups x (2kb x 2nt x 2streams) = 8 loads each
#define GSEG2N(AP0, AP1, ACC)                                                \
  { const short* p0_ = (AP0) + abase;                                        \
    const short* p1_ = (AP1) + abase;                                        \
    short8 abuf[2][8]; /* [buf][kk*4 + stream*2 + nt] */                     \
    _Pragma("unroll")                                                        \
    for (int u_ = 0; u_ < 2; ++u_) {                                         \
      abuf[0][u_*4+0] = cohld16(p0_ + LOFF(u_, 0));                          \
      abuf[0][u_*4+1] = cohld16(p0_ + LOFF(u_, 1));                          \
      abuf[0][u_*4+2] = cohld16(p1_ + LOFF(u_, 0));                          \
      abuf[0][u_*4+3] = cohld16(p1_ + LOFF(u_, 1));                          \
    }                                                                        \
    _Pragma("unroll")                                                        \
    for (int g = 0; g < 8; ++g) {                                            \
      if (g < 7) {                                                           \
        _Pragma("unroll")                                                    \
        for (int u_ = 0; u_ < 2; ++u_) {                                     \
          const int kb = (g+1)*2 + u_;                                       \
          abuf[(g+1)&1][u_*4+0] = cohld16(p0_ + LOFF(kb, 0));                \
          abuf[(g+1)&1][u_*4+1] = cohld16(p0_ + LOFF(kb, 1));                \
          abuf[(g+1)&1][u_*4+2] = cohld16(p1_ + LOFF(kb, 0));                \
          abuf[(g+1)&1][u_*4+3] = cohld16(p1_ + LOFF(kb, 1));                \
        }                                                                    \
        WAITV(8);                                                            \
      } else { WAITV(0); }                                                   \
      _Pragma("unroll")                                                      \
      for (int kk = 0; kk < 2; ++kk) {                                       \
        const int kb = g*2 + kk;                                             \
        _Pragma("unroll")                                                    \
        for (int mt = 0; mt < 4; ++mt) {                                     \
          short8 w0 = *(const short8*)&Wl[0][kb*4 + q][mt*16 + ln][0];       \
          short8 w1 = *(const short8*)&Wl[1][kb*4 + q][mt*16 + ln][0];       \
          _Pragma("unroll")                                                  \
          for (int nt = 0; nt < 2; ++nt) {                                   \
            ACC[mt][nt] = __builtin_amdgcn_mfma_f32_16x16x32_bf16(           \
                w0, abuf[g&1][kk*4 + nt], ACC[mt][nt], 0, 0, 0);             \
            ACC[mt][nt] = __builtin_amdgcn_mfma_f32_16x16x32_bf16(           \
                w1, abuf[g&1][kk*4 + 2 + nt], ACC[mt][nt], 0, 0, 0);         \
          }                                                                  \
        }                                                                    \
      }                                                                      \
    } }

// in-lane epilogue: lane holds gates i,f,g,o of (unit=U0+mt*4+q, batch) in
// ACC[mt][nt][0..3]. MODE 0: sv = x[b][TV]; 1: none; 2: sv = obuf[b].
// Repack h through 4KB LDS, then coalesced 16B sc0sc1 stores.
#define EPI16(ACC, MODE, TV, HOUT)                                           \
  { float sv[2];                                                             \
    _Pragma("unroll")                                                        \
    for (int nt = 0; nt < 2; ++nt) {                                         \
      const int bl = wv*32 + nt*16 + ln;                                     \
      sv[nt] = ((MODE) == 0) ? ldf(x, (long)(B0 + bl)*TT + (TV), dt)         \
             : ((MODE) == 2) ? obuf[bl] : 0.f;                               \
    }                                                                        \
    _Pragma("unroll")                                                        \
    for (int mt = 0; mt < 4; ++mt) {                                         \
      const int u = mt*4 + q;                                                \
      _Pragma("unroll")                                                      \
      for (int nt = 0; nt < 2; ++nt) {                                       \
        float gi = ACC[mt][nt][0] + bs[u*4+0];                               \
        float gf = ACC[mt][nt][1] + bs[u*4+1];                               \
        float gg = ACC[mt][nt][2] + bs[u*4+2];                               \
        float go = ACC[mt][nt][3] + bs[u*4+3];                               \
        if ((MODE) != 1) {                                                   \
          gi += sv[nt]*wih[u*4+0]; gf += sv[nt]*wih[u*4+1];                  \
          gg += sv[nt]*wih[u*4+2]; go += sv[nt]*wih[u*4+3];                  \
        }                                                                    \
        const float I = 1.f/(1.f+expf(-gi));                                 \
        const float F = 1.f/(1.f+expf(-gf));                                 \
        const float G = tanhf(gg);                                           \
        const float O = 1.f/(1.f+expf(-go));                                 \
        const float cn = F*cst[mt][nt] + I*G;                                \
        cst[mt][nt] = cn;                                                    \
        hbuf[wv*32 + nt*16 + ln][u] = f2bf(O * tanhf(cn));                   \
      }                                                                      \
    }                                                                        \
    __syncthreads();                                                         \
    { const int b_ = tid >> 1, hf_ = tid & 1;                                \
      short8 hv = *(const short8*)&hbuf[b_][hf_*8];                          \
      cohst16((HOUT) + (long)(B0 + b_)*512 + U0 + hf_*8, hv); } }

// fence-free barrier: 8 groups of 16, per-group release line
#define GBAR()                                                               \
  { __syncthreads();                                                         \
    ++ph;                                                                    \
    if (tid == 0) {                                                          \
      asm volatile("s_waitcnt vmcnt(0)" ::: "memory");                       \
      __hip_atomic_fetch_add(grpArr, 1, __ATOMIC_RELAXED,                    \
                             __HIP_MEMORY_SCOPE_SYSTEM);                     \
      if (isMaster) {                                                        \
        while (__hip_atomic_load(grpArr, __ATOMIC_RELAXED,                   \
                                 __HIP_MEMORY_SCOPE_SYSTEM) < ph * 16)       \
          __builtin_amdgcn_s_sleep(1);                                       \
        __hip_atomic_fetch_add(ctr, 1, __ATOMIC_RELAXED,                     \
                               __HIP_MEMORY_SCOPE_SYSTEM);                   \
        while (__hip_atomic_load(ctr, __ATOMIC_RELAXED,                      \
                                 __HIP_MEMORY_SCOPE_SYSTEM) < ph * 8)        \
          __builtin_amdgcn_s_sleep(1);                                       \
        __hip_atomic_store(grpRel, ph, __ATOMIC_RELAXED,                     \
                           __HIP_MEMORY_SCOPE_SYSTEM);                       \
      } else {                                                               \
        while (__hip_atomic_load(grpRel, __ATOMIC_RELAXED,                   \
                                 __HIP_MEMORY_SCOPE_SYSTEM) < ph)            \
          __builtin_amdgcn_s_sleep(1);                                       \
      }                                                                      \
    }                                                                        \
    __syncthreads();                                                         \
  }

// pipelined head (2-deep, single latency): only L0-role runs this
#define HEADP(H1C, FW, FB, S)                                                \
  { const int hb = tid >> 1, hf = tid & 1;                                   \
    const short* hp = (H1C) + (long)(B0 + hb)*512 + hf*256;                  \
    float sum = 0.f;                                                         \
    short8 hbu[2][8];                                                        \
    _Pragma("unroll")                                                        \
    for (int i = 0; i < 8; ++i) hbu[0][i] = cohld16(hp + i*8);               \
    _Pragma("unroll")                                                        \
    for (int g4 = 0; g4 < 4; ++g4) {                                         \
      if (g4 < 3) {                                                          \
        _Pragma("unroll")                                                    \
        for (int i = 0; i < 8; ++i)                                          \
          hbu[(g4+1)&1][i] = cohld16(hp + ((g4+1)*8 + i)*8);                 \
        WAITV(8);                                                            \
      } else { WAITV(0); }                                                   \
      _Pragma("unroll")                                                      \
      for (int i = 0; i < 8; ++i)                                            \
        _Pragma("unroll")                                                    \
        for (int j = 0; j < 8; ++j)                                          \
          sum += bf2f(hbu[g4&1][i][j]) *                                     \
                 ldf((FW), hf*256 + (g4*8+i)*8 + j, dt);                     \
    }                                                                        \
    sum += __shfl_xor(sum, 1);                                               \
    if (hf == 0) {                                                           \
      float o = sum + ldf((FB), 0, dt);                                      \
      obuf[hb] = o;                                                          \
      if (ug == 0) dout[(long)(B0 + hb)*FUT + (S)] = o;                      \
    }                                                                        \
    __syncthreads();                                                         \
  }

  // ---- one-time staging: warmup weights + biases ----
  if (role == 0) {
    STAGE16(0, Whh0);
    BIAS16(b_ih0, b_hh0, w_ih0);
  } else {
    STAGE16(0, Wih1); STAGE16(1, Whh1);
    BIAS16(b_ih1, b_hh1, (const void*)0);
  }
  __syncthreads();

  // ---- warmup: phase t = L0(t) on role0 || L1(t-1) on role1 ----
  for (int t = 0; t < TT; ++t) {
    if (role == 0) {
      floatx4 a[4][2]; ZACC(a);
      GSEG1N(h0c, a);
      EPI16(a, 0, t, h0n);
    } else if (t > 0) {
      floatx4 a[4][2]; ZACC(a);
      GSEG2N(h0c, h1c, a);
      EPI16(a, 1, 0, h1n);
    }
    GBAR();
    { short* t_ = h0c; h0c = h0n; h0n = t_; }
    if (t > 0) { short* t_ = h1c; h1c = h1n; h1n = t_; }
  }
  // final L1(511)
  if (role == 1) {
    floatx4 a[4][2]; ZACC(a);
    GSEG2N(h0c, h1c, a);
    EPI16(a, 1, 0, h1n);
  }
  GBAR();
  { short* t_ = h1c; h1c = h1n; h1n = t_; }
  if (role == 0) HEADP(h1c, fc_w, fc_b, 0);

  // ---- transition: stage decode weights + biases (block-local) ----
  if (role == 0) {
    STAGE16(0, pWhh0);
    BIAS16(pb_ih0, pb_hh0, pw_ih0);
  } else {
    STAGE16(0, pWih1); STAGE16(1, pWhh1);
    BIAS16(pb_ih1, pb_hh1, (const void*)0);
  }
  __syncthreads();

  // ---- decode: 63 steps, 2 barriers each; c-state carried in-lane ----
  for (int s = 1; s < FUT; ++s) {
    if (role == 0) {
      floatx4 a[4][2]; ZACC(a);
      GSEG1N(h0c, a);
      EPI16(a, 2, 0, h0n);
    }
    GBAR();
    { short* t_ = h0c; h0c = h0n; h0n = t_; }
    if (role == 1) {
      floatx4 a[4][2]; ZACC(a);
      GSEG2N(h0c, h1c, a);
      EPI16(a, 1, 0, h1n);
    }
    GBAR();
    { short* t_ = h1c; h1c = h1n; h1n = t_; }
    if (role == 0) HEADP(h1c, pfc_w, pfc_b, s);
  }
#undef STAGE16
#undef BIAS16
#undef ZACC
#undef LOFF
#undef GSEG1N
#undef GSEG2N
#undef EPI16
#undef GBAR
#undef HEADP
}

extern "C" void kernel_launch(void* const* d_in, const int* in_sizes, int n_in,
                              void* d_out, int out_size, void* d_ws, size_t ws_size,
                              hipStream_t stream) {
  float* dout = (float*)d_out;

  static const int exp_sizes[22] = {
    131072, 1, 2048, 1048576, 2048, 2048, 1048576, 1048576, 2048, 2048,
    512, 1, 2048, 1048576, 2048, 2048, 1048576, 1048576, 2048, 2048, 512, 1};
  int code = -1, m = 0;
  if (n_in != 22) { code = 0; m = n_in & 127; }
  else {
    for (int i = 0; i < 22; ++i)
      if (in_sizes[i] != exp_sizes[i]) { code = 1; m = i; break; }
  }
  if (code < 0 && out_size != BB * FUT) { code = 6; m = (out_size >> 8) & 127; }
  if (code < 0 && (d_ws == nullptr || ws_size < NEED_WS)) {
    code = 2; m = (int)(ws_size >> 20); if (m > 127) m = 127;
  }
  if (code >= 0) {
    float v = ldexpf(1.f + (float)m / 128.f, 20 + code);
    beacon_kernel<<<dim3(1), dim3(64), 0, stream>>>(dout, v);
    return;
  }

  const void* x      = d_in[0];
  const void* w_ih0  = d_in[2];
  const void* w_hh0  = d_in[3];
  const void* b_ih0  = d_in[4];
  const void* b_hh0  = d_in[5];
  const void* w_ih1  = d_in[6];
  const void* w_hh1  = d_in[7];
  const void* b_ih1  = d_in[8];
  const void* b_hh1  = d_in[9];
  const void* fc_w   = d_in[10];
  const void* fc_b   = d_in[11];
  const void* pw_ih0 = d_in[12];
  const void* pw_hh0 = d_in[13];
  const void* pb_ih0 = d_in[14];
  const void* pb_hh0 = d_in[15];
  const void* pw_ih1 = d_in[16];
  const void* pw_hh1 = d_in[17];
  const void* pb_ih1 = d_in[18];
  const void* pb_hh1 = d_in[19];
  const void* pfc_w  = d_in[20];
  const void* pfc_b  = d_in[21];

  char* ws = (char*)d_ws;
  Hdr* hdr = (Hdr*)ws;
  int* ctr = (int*)(ws + OFF_CTR);
  short* Wc[6];
  for (int i = 0; i < 6; ++i) Wc[i] = (short*)(ws + OFF_W + (size_t)i*WSZ);
  short* H0a = (short*)(ws + OFF_H);
  short* H0b = (short*)(ws + OFF_H + HSZ);
  short* H1a = (short*)(ws + OFF_H + 2*HSZ);
  short* H1b = (short*)(ws + OFF_H + 3*HSZ);

  hipMemsetAsync(ws, 0, 8192, stream);          // hdr + barrier counters
  hipMemsetAsync(H0a, 0, HSZ, stream);
  hipMemsetAsync(H1a, 0, HSZ, stream);
  probe1_kernel<<<dim3(1), dim3(256), 0, stream>>>(w_hh0, hdr);

  dim3 cg(1024), cb(256);
  cvt_kernel<<<cg, cb, 0, stream>>>(w_hh0,  Wc[0], hdr);
  cvt_kernel<<<cg, cb, 0, stream>>>(w_ih1,  Wc[1], hdr);
  cvt_kernel<<<cg, cb, 0, stream>>>(w_hh1,  Wc[2], hdr);
  cvt_kernel<<<cg, cb, 0, stream>>>(pw_hh0, Wc[3], hdr);
  cvt_kernel<<<cg, cb, 0, stream>>>(pw_ih1, Wc[4], hdr);
  cvt_kernel<<<cg, cb, 0, stream>>>(pw_hh1, Wc[5], hdr);

  lstm_persist<<<dim3(NBLK), dim3(256), 0, stream>>>(
      x, w_ih0, b_ih0, b_hh0, b_ih1, b_hh1, fc_w, fc_b,
      pw_ih0, pb_ih0, pb_hh0, pb_ih1, pb_hh1, pfc_w, pfc_b,
      Wc[0], Wc[1], Wc[2], Wc[3], Wc[4], Wc[5],
      H0a, H0b, H1a, H1b, ctr, hdr, dout);
}